// Round 4
// baseline (25.570 us; speedup 1.0000x reference)
//
#include <hip/hip_runtime.h>
#include <hip/hip_bf16.h>

// x: [32768, 3, 16, 16] f32 ; lhs: [2, 16, 8] ; rhs: [2, 8, 16] ; W: [1, 3072] ; b: [1]
// out: [32768] f32
//
// Algebraic collapse (verified R1-R3, absmax <= 1e-3):
//   out[b] = dot(x[b] (768 f32), Weff (768 f32)) + bias
//   Weff[ch, r*8+p, c*8+q] = sum_{P,Q} lhs[r,P,p] * rhs[c,q,Q]
//                            * W[ch*1024 + (r*16+P)*32 + (c*16+Q)]
//
// R4: two kernels. Kernel 1 computes Weff ONCE into d_ws (3 KB) via the
// two-stage LDS contraction (1 block x 256 threads, ~1.5 us). Kernel 2 is
// R3's streaming structure minus the per-block contraction: per thread
// 3 weff float4 (L1-hot) + 12 x float4 + 48 FMA + merged 4-row reduction.
// This removes ~196 KB/block of redundant L1 traffic that was contending
// with the HBM x-stream in R3.

#define BATCH 32768
#define ROW_F4 192              // 768 floats per sample in float4 units
#define ROWS_PER_BLOCK 16
#define GRID_BLOCKS (BATCH / ROWS_PER_BLOCK)   // 2048

__device__ __forceinline__ float dot4(const float4& a, const float4& b) {
    return a.x * b.x + a.y * b.y + a.z * b.z + a.w * b.w;
}

// ---------------- kernel 1: build Weff once (1 block x 256 threads) --------
__global__ __launch_bounds__(256) void build_weff_kernel(
        const float* __restrict__ lhs,
        const float4* __restrict__ rhs4,
        const float4* __restrict__ W4,
        float* __restrict__ weff_out) {
    __shared__ float tmp[1536];                 // [ch][R(32)][j(16)]
    const int tid = threadIdx.x;

    // stage A: tmp[ch,R,j] = sum_Q rhs[c,q,Q] * W[ch*1024 + R*32 + c*16 + Q]
    #pragma unroll
    for (int s = 0; s < 6; ++s) {
        int idx = tid + (s << 8);           // 0..1535
        int ch  = idx >> 9;
        int rem = idx & 511;
        int R   = rem >> 4;
        int j   = rem & 15;
        int c   = j >> 3;
        int q   = j & 7;
        const float4* rp = rhs4 + c * 32 + q * 4;            // 16 floats
        const float4* wp = W4 + ch * 256 + R * 8 + c * 4;    // 16 floats
        tmp[idx] = dot4(rp[0], wp[0]) + dot4(rp[1], wp[1])
                 + dot4(rp[2], wp[2]) + dot4(rp[3], wp[3]);
    }
    __syncthreads();

    // stage B: weff[ch,i,j] = sum_P lhs[r*128 + P*8 + p] * tmp[ch*512 + (r*16+P)*16 + j]
    #pragma unroll
    for (int s = 0; s < 3; ++s) {
        int idx = tid + (s << 8);           // 0..767
        int ch  = idx >> 8;
        int rem = idx & 255;
        int i   = rem >> 4;
        int j   = rem & 15;
        int r   = i >> 3;
        int p   = i & 7;
        const float* lp = lhs + r * 128 + p;
        const float* tp = tmp + ch * 512 + r * 256 + j;
        float acc = 0.f;
        #pragma unroll
        for (int P = 0; P < 16; ++P) acc += lp[P * 8] * tp[P * 16];
        weff_out[idx] = acc;
    }
}

// ---------------- kernel 2: stream x, dot with cached weff -----------------
// Merged 4-row wave64 reduction: 10 shfl instead of 24.
__device__ __forceinline__ void reduce4_store(float a0, float a1, float a2, float a3,
                                              int lane, float* __restrict__ outp,
                                              float bias) {
    a0 += __shfl_xor(a0, 1);
    a1 += __shfl_xor(a1, 1);
    a2 += __shfl_xor(a2, 1);
    a3 += __shfl_xor(a3, 1);
    float b0 = (lane & 1) ? a1 : a0;   // row (lane&1)
    float b1 = (lane & 1) ? a3 : a2;   // row 2+(lane&1)
    b0 += __shfl_xor(b0, 2);
    b1 += __shfl_xor(b1, 2);
    float c = (lane & 2) ? b1 : b0;    // row (lane&3)
    c += __shfl_xor(c, 4);
    c += __shfl_xor(c, 8);
    c += __shfl_xor(c, 16);
    c += __shfl_xor(c, 32);
    if (lane < 4) outp[lane] = c + bias;
}

__global__ __launch_bounds__(256, 4) void stream_dot_kernel(
        const float4* __restrict__ x4,
        const float4* __restrict__ w4,    // weff in d_ws, 192 float4
        const float* __restrict__ bptr,
        float* __restrict__ out) {
    const int tid  = threadIdx.x;
    const int lane = tid & 63;
    const int w    = tid >> 6;

    const int row0 = blockIdx.x * ROWS_PER_BLOCK + w * 4;   // 4 rows per wave

    // issue the x load-batch first (HBM, long latency)
    const float4* xr = x4 + (size_t)row0 * ROW_F4 + lane;
    float4 xv[4][3];
    #pragma unroll
    for (int rr = 0; rr < 4; ++rr)
        #pragma unroll
        for (int k = 0; k < 3; ++k)
            xv[rr][k] = xr[rr * ROW_F4 + k * 64];

    // weff fragment (3 KB total, L1-hot after first round) + bias
    const float4 wv0 = w4[lane];
    const float4 wv1 = w4[lane + 64];
    const float4 wv2 = w4[lane + 128];
    const float  bias = bptr[0];

    float a0 = dot4(xv[0][0], wv0) + dot4(xv[0][1], wv1) + dot4(xv[0][2], wv2);
    float a1 = dot4(xv[1][0], wv0) + dot4(xv[1][1], wv1) + dot4(xv[1][2], wv2);
    float a2 = dot4(xv[2][0], wv0) + dot4(xv[2][1], wv1) + dot4(xv[2][2], wv2);
    float a3 = dot4(xv[3][0], wv0) + dot4(xv[3][1], wv1) + dot4(xv[3][2], wv2);
    reduce4_store(a0, a1, a2, a3, lane, out + row0, bias);
}

extern "C" void kernel_launch(void* const* d_in, const int* in_sizes, int n_in,
                              void* d_out, int out_size, void* d_ws, size_t ws_size,
                              hipStream_t stream) {
    const float* x   = (const float*)d_in[0];   // [32768, 3, 16, 16]
    const float* lhs = (const float*)d_in[1];   // [2, 16, 8]
    const float* rhs = (const float*)d_in[2];   // [2, 8, 16]
    const float* W   = (const float*)d_in[3];   // [1, 3072]
    const float* b   = (const float*)d_in[4];   // [1]
    float* out = (float*)d_out;                 // [32768]

    float* weff = (float*)d_ws;                 // 768 floats = 3 KB

    build_weff_kernel<<<1, 256, 0, stream>>>(
        lhs, (const float4*)rhs, (const float4*)W, weff);

    stream_dot_kernel<<<GRID_BLOCKS, 256, 0, stream>>>(
        (const float4*)x, (const float4*)weff, b, out);
}

// Round 5
// 21.700 us; speedup vs baseline: 1.1783x; 1.1783x over previous
//
#include <hip/hip_runtime.h>
#include <hip/hip_bf16.h>

// x: [32768, 3, 16, 16] f32 ; lhs: [2, 16, 8] ; rhs: [2, 8, 16] ; W: [1, 3072] ; b: [1]
// out: [32768] f32
//
// Algebraic collapse (verified R1-R4, absmax <= 1e-3):
//   out[b] = dot(x[b] (768 f32), Weff (768 f32)) + bias
//   Weff[ch, r*8+p, c*8+q] = sum_{P,Q} lhs[r,P,p] * rhs[c,q,Q]
//                            * W[ch*1024 + (r*16+P)*32 + (c*16+Q)]
//
// R5: fused (R3 structure) but the per-block weff contraction now reads
// W/rhs/lhs from LDS, staged once per block with each byte fetched exactly
// once (~14 KB/block through L1 instead of ~96 KB of redundant broadcast
// re-reads). This unloads the L1/TD pipe that was contending with the HBM
// x-stream in R3.

#define BATCH 32768
#define ROW_F4 192              // 768 floats per sample in float4 units
#define ROWS_PER_BLOCK 16
#define GRID_BLOCKS (BATCH / ROWS_PER_BLOCK)   // 2048

__device__ __forceinline__ float dot4(const float4& a, const float4& b) {
    return a.x * b.x + a.y * b.y + a.z * b.z + a.w * b.w;
}

// Merged 4-row wave64 reduction: 10 shfl instead of 24.
__device__ __forceinline__ void reduce4_store(float a0, float a1, float a2, float a3,
                                              int lane, float* __restrict__ outp,
                                              float bias) {
    a0 += __shfl_xor(a0, 1);
    a1 += __shfl_xor(a1, 1);
    a2 += __shfl_xor(a2, 1);
    a3 += __shfl_xor(a3, 1);
    float b0 = (lane & 1) ? a1 : a0;   // row (lane&1)
    float b1 = (lane & 1) ? a3 : a2;   // row 2+(lane&1)
    b0 += __shfl_xor(b0, 2);
    b1 += __shfl_xor(b1, 2);
    float c = (lane & 2) ? b1 : b0;    // row (lane&3)
    c += __shfl_xor(c, 4);
    c += __shfl_xor(c, 8);
    c += __shfl_xor(c, 16);
    c += __shfl_xor(c, 32);
    if (lane < 4) outp[lane] = c + bias;
}

__global__ __launch_bounds__(256, 4) void fused_compressor_kernel(
        const float4* __restrict__ x4,
        const float4* __restrict__ lhs4,   // 64 float4
        const float4* __restrict__ rhs4,   // 64 float4
        const float4* __restrict__ W4,     // 768 float4
        const float* __restrict__ bptr,
        float* __restrict__ out) {
    // LDS: staged params + contraction temporaries
    __shared__ __align__(16) float Wl[3072];    // W copy
    __shared__ __align__(16) float rh[256];     // rhs copy
    __shared__ __align__(16) float lh[256];     // lhs copy
    __shared__ float tmp[1536];                 // [ch][R(32)][j(16)]
    __shared__ __align__(16) float weff[768];   // [ch][i(16)][j(16)]

    const int tid  = threadIdx.x;
    const int lane = tid & 63;
    const int w    = tid >> 6;

    const int row0 = blockIdx.x * ROWS_PER_BLOCK + w * 4;   // 4 rows per wave

    // ---- issue x load-batch first (12 x 1KB per wave, HBM) ----
    const float4* xr = x4 + (size_t)row0 * ROW_F4 + lane;
    float4 xv[4][3];
    #pragma unroll
    for (int rr = 0; rr < 4; ++rr)
        #pragma unroll
        for (int k = 0; k < 3; ++k)
            xv[rr][k] = xr[rr * ROW_F4 + k * 64];

    // ---- stage params into LDS, each byte read once (coalesced float4) ----
    // W: 768 float4 -> 3 per thread
    float4 wreg0 = W4[tid];
    float4 wreg1 = W4[tid + 256];
    float4 wreg2 = W4[tid + 512];
    // rhs/lhs: 64 float4 each -> threads 0-63 / 64-127
    float4 sreg;
    if (tid < 128) sreg = (tid < 64) ? rhs4[tid] : lhs4[tid - 64];

    reinterpret_cast<float4*>(Wl)[tid]       = wreg0;
    reinterpret_cast<float4*>(Wl)[tid + 256] = wreg1;
    reinterpret_cast<float4*>(Wl)[tid + 512] = wreg2;
    if (tid < 128) {
        if (tid < 64) reinterpret_cast<float4*>(rh)[tid] = sreg;
        else          reinterpret_cast<float4*>(lh)[tid - 64] = sreg;
    }
    __syncthreads();

    // ---- stage A (from LDS): tmp[ch,R,j] = sum_Q rhs[c,q,Q]*W[ch,R,c*16+Q] ----
    const float4* rhv = reinterpret_cast<const float4*>(rh);
    const float4* Wlv = reinterpret_cast<const float4*>(Wl);
    #pragma unroll
    for (int s = 0; s < 6; ++s) {
        int idx = tid + (s << 8);           // 0..1535
        int ch  = idx >> 9;
        int rem = idx & 511;
        int R   = rem >> 4;
        int j   = rem & 15;
        int c   = j >> 3;
        int q   = j & 7;
        const float4* rp = rhv + c * 32 + q * 4;             // 16 floats
        const float4* wp = Wlv + ch * 256 + R * 8 + c * 4;   // 16 floats
        tmp[idx] = dot4(rp[0], wp[0]) + dot4(rp[1], wp[1])
                 + dot4(rp[2], wp[2]) + dot4(rp[3], wp[3]);
    }
    __syncthreads();

    // ---- stage B (from LDS): weff[ch,i,j] = sum_P lhs[r,P,p]*tmp[ch,r*16+P,j] ----
    #pragma unroll
    for (int s = 0; s < 3; ++s) {
        int idx = tid + (s << 8);           // 0..767
        int ch  = idx >> 8;
        int rem = idx & 255;
        int i   = rem >> 4;
        int j   = rem & 15;
        int r   = i >> 3;
        int p   = i & 7;
        const float* lp = lh + r * 128 + p;
        const float* tp = tmp + ch * 512 + r * 256 + j;
        float acc = 0.f;
        #pragma unroll
        for (int P = 0; P < 16; ++P) acc += lp[P * 8] * tp[P * 16];
        weff[idx] = acc;
    }
    __syncthreads();

    // ---- per-lane weight fragment (LDS) + bias ----
    const float4* w4 = reinterpret_cast<const float4*>(weff);
    const float4 wv0 = w4[lane];
    const float4 wv1 = w4[lane + 64];
    const float4 wv2 = w4[lane + 128];
    const float  bias = bptr[0];

    // ---- compute (x loads drained at the first barrier; data in regs) ----
    float a0 = dot4(xv[0][0], wv0) + dot4(xv[0][1], wv1) + dot4(xv[0][2], wv2);
    float a1 = dot4(xv[1][0], wv0) + dot4(xv[1][1], wv1) + dot4(xv[1][2], wv2);
    float a2 = dot4(xv[2][0], wv0) + dot4(xv[2][1], wv1) + dot4(xv[2][2], wv2);
    float a3 = dot4(xv[3][0], wv0) + dot4(xv[3][1], wv1) + dot4(xv[3][2], wv2);
    reduce4_store(a0, a1, a2, a3, lane, out + row0, bias);
}

extern "C" void kernel_launch(void* const* d_in, const int* in_sizes, int n_in,
                              void* d_out, int out_size, void* d_ws, size_t ws_size,
                              hipStream_t stream) {
    const float* x   = (const float*)d_in[0];   // [32768, 3, 16, 16]
    const float* lhs = (const float*)d_in[1];   // [2, 16, 8]
    const float* rhs = (const float*)d_in[2];   // [2, 8, 16]
    const float* W   = (const float*)d_in[3];   // [1, 3072]
    const float* b   = (const float*)d_in[4];   // [1]
    float* out = (float*)d_out;                 // [32768]

    fused_compressor_kernel<<<GRID_BLOCKS, 256, 0, stream>>>(
        (const float4*)x, (const float4*)lhs, (const float4*)rhs,
        (const float4*)W, b, out);
}

// Round 6
// 21.693 us; speedup vs baseline: 1.1788x; 1.0004x over previous
//
#include <hip/hip_runtime.h>
#include <hip/hip_bf16.h>

// x: [32768, 3, 16, 16] f32 ; lhs: [2, 16, 8] ; rhs: [2, 8, 16] ; W: [1, 3072] ; b: [1]
// out: [32768] f32
//
// Algebraic collapse (verified R1-R5, absmax <= 1e-3):
//   out[b] = dot(x[b] (768 f32), Weff (768 f32)) + bias
//   Weff[ch, r*8+p, c*8+q] = sum_{P,Q} lhs[r,P,p] * rhs[c,q,Q]
//                            * W[ch*1024 + (r*16+P)*32 + (c*16+Q)]
//
// R6: R5 structure with the load ORDER fixed: param loads issue FIRST, x
// loads second (sched_barrier-pinned). The LDS param write then waits only
// vmcnt(12), so the 48 KB/block x-stream stays in flight THROUGH the weff
// contraction (in R5, x-first forced vmcnt(0) -> the contraction ran with
// zero HBM demand and per-CU demand was bursty).

#define BATCH 32768
#define ROW_F4 192              // 768 floats per sample in float4 units
#define ROWS_PER_BLOCK 16
#define GRID_BLOCKS (BATCH / ROWS_PER_BLOCK)   // 2048

__device__ __forceinline__ float dot4(const float4& a, const float4& b) {
    return a.x * b.x + a.y * b.y + a.z * b.z + a.w * b.w;
}

// Merged 4-row wave64 reduction: 10 shfl instead of 24.
__device__ __forceinline__ void reduce4_store(float a0, float a1, float a2, float a3,
                                              int lane, float* __restrict__ outp,
                                              float bias) {
    a0 += __shfl_xor(a0, 1);
    a1 += __shfl_xor(a1, 1);
    a2 += __shfl_xor(a2, 1);
    a3 += __shfl_xor(a3, 1);
    float b0 = (lane & 1) ? a1 : a0;   // row (lane&1)
    float b1 = (lane & 1) ? a3 : a2;   // row 2+(lane&1)
    b0 += __shfl_xor(b0, 2);
    b1 += __shfl_xor(b1, 2);
    float c = (lane & 2) ? b1 : b0;    // row (lane&3)
    c += __shfl_xor(c, 4);
    c += __shfl_xor(c, 8);
    c += __shfl_xor(c, 16);
    c += __shfl_xor(c, 32);
    if (lane < 4) outp[lane] = c + bias;
}

__global__ __launch_bounds__(256, 4) void fused_compressor_kernel(
        const float4* __restrict__ x4,
        const float4* __restrict__ lhs4,   // 64 float4
        const float4* __restrict__ rhs4,   // 64 float4
        const float4* __restrict__ W4,     // 768 float4
        const float* __restrict__ bptr,
        float* __restrict__ out) {
    __shared__ __align__(16) float Wl[3072];    // W copy (12 KB)
    __shared__ __align__(16) float rh[256];     // rhs copy
    __shared__ __align__(16) float lh[256];     // lhs copy
    __shared__ float tmp[1536];                 // [ch][R(32)][j(16)]
    __shared__ __align__(16) float weff[768];   // [ch][i(16)][j(16)]

    const int tid  = threadIdx.x;
    const int lane = tid & 63;
    const int w    = tid >> 6;

    const int row0 = blockIdx.x * ROWS_PER_BLOCK + w * 4;   // 4 rows per wave

    // ---- 1) param loads FIRST (4 per thread, branch-free) ----
    float4 wreg0 = W4[tid];
    float4 wreg1 = W4[tid + 256];
    float4 wreg2 = W4[tid + 512];
    int sidx = tid & 127;                       // 0-63: rhs, 64-127: lhs (dup for 128+)
    float4 sreg = (sidx < 64) ? rhs4[sidx] : lhs4[sidx - 64];
    __builtin_amdgcn_sched_barrier(0);          // pin: params issued before x

    // ---- 2) x load-batch second (12 x 1KB per wave); stays in flight
    //         through the contraction (waits below are vmcnt(12)) ----
    const float4* xr = x4 + (size_t)row0 * ROW_F4 + lane;
    float4 xv[4][3];
    #pragma unroll
    for (int rr = 0; rr < 4; ++rr)
        #pragma unroll
        for (int k = 0; k < 3; ++k)
            xv[rr][k] = xr[rr * ROW_F4 + k * 64];
    __builtin_amdgcn_sched_barrier(0);          // pin: x issued before LDS writes

    // ---- 3) write params to LDS (waits only the 4 param loads) ----
    reinterpret_cast<float4*>(Wl)[tid]       = wreg0;
    reinterpret_cast<float4*>(Wl)[tid + 256] = wreg1;
    reinterpret_cast<float4*>(Wl)[tid + 512] = wreg2;
    if (tid < 128) {
        if (tid < 64) reinterpret_cast<float4*>(rh)[tid] = sreg;
        else          reinterpret_cast<float4*>(lh)[tid - 64] = sreg;
    }
    __syncthreads();

    // ---- stage A (LDS): tmp[ch,R,j] = sum_Q rhs[c,q,Q]*W[ch,R,c*16+Q] ----
    const float4* rhv = reinterpret_cast<const float4*>(rh);
    const float4* Wlv = reinterpret_cast<const float4*>(Wl);
    #pragma unroll
    for (int s = 0; s < 6; ++s) {
        int idx = tid + (s << 8);           // 0..1535
        int ch  = idx >> 9;
        int rem = idx & 511;
        int R   = rem >> 4;
        int j   = rem & 15;
        int c   = j >> 3;
        int q   = j & 7;
        const float4* rp = rhv + c * 32 + q * 4;             // 16 floats
        const float4* wp = Wlv + ch * 256 + R * 8 + c * 4;   // 16 floats
        tmp[idx] = dot4(rp[0], wp[0]) + dot4(rp[1], wp[1])
                 + dot4(rp[2], wp[2]) + dot4(rp[3], wp[3]);
    }
    __syncthreads();

    // ---- stage B (LDS): weff[ch,i,j] = sum_P lhs[r,P,p]*tmp[ch,r*16+P,j] ----
    #pragma unroll
    for (int s = 0; s < 3; ++s) {
        int idx = tid + (s << 8);           // 0..767
        int ch  = idx >> 8;
        int rem = idx & 255;
        int i   = rem >> 4;
        int j   = rem & 15;
        int r   = i >> 3;
        int p   = i & 7;
        const float* lp = lh + r * 128 + p;
        const float* tp = tmp + ch * 512 + r * 256 + j;
        float acc = 0.f;
        #pragma unroll
        for (int P = 0; P < 16; ++P) acc += lp[P * 8] * tp[P * 16];
        weff[idx] = acc;
    }
    __syncthreads();

    // ---- per-lane weight fragment (LDS) + bias ----
    const float4* w4 = reinterpret_cast<const float4*>(weff);
    const float4 wv0 = w4[lane];
    const float4 wv1 = w4[lane + 64];
    const float4 wv2 = w4[lane + 128];
    const float  bias = bptr[0];

    // ---- compute: x drains here (vmcnt(0) before first use) ----
    float a0 = dot4(xv[0][0], wv0) + dot4(xv[0][1], wv1) + dot4(xv[0][2], wv2);
    float a1 = dot4(xv[1][0], wv0) + dot4(xv[1][1], wv1) + dot4(xv[1][2], wv2);
    float a2 = dot4(xv[2][0], wv0) + dot4(xv[2][1], wv1) + dot4(xv[2][2], wv2);
    float a3 = dot4(xv[3][0], wv0) + dot4(xv[3][1], wv1) + dot4(xv[3][2], wv2);
    reduce4_store(a0, a1, a2, a3, lane, out + row0, bias);
}

extern "C" void kernel_launch(void* const* d_in, const int* in_sizes, int n_in,
                              void* d_out, int out_size, void* d_ws, size_t ws_size,
                              hipStream_t stream) {
    const float* x   = (const float*)d_in[0];   // [32768, 3, 16, 16]
    const float* lhs = (const float*)d_in[1];   // [2, 16, 8]
    const float* rhs = (const float*)d_in[2];   // [2, 8, 16]
    const float* W   = (const float*)d_in[3];   // [1, 3072]
    const float* b   = (const float*)d_in[4];   // [1]
    float* out = (float*)d_out;                 // [32768]

    fused_compressor_kernel<<<GRID_BLOCKS, 256, 0, stream>>>(
        (const float4*)x, (const float4*)lhs, (const float4*)rhs,
        (const float4*)W, b, out);
}

// Round 7
// 20.637 us; speedup vs baseline: 1.2390x; 1.0511x over previous
//
#include <hip/hip_runtime.h>
#include <hip/hip_bf16.h>

// x: [32768, 3, 16, 16] f32 ; lhs: [2, 16, 8] ; rhs: [2, 8, 16] ; W: [1, 3072] ; b: [1]
// out: [32768] f32
//
// Algebraic collapse (verified R1-R6, absmax <= 1e-3):
//   out[b] = dot(x[b] (768 f32), Weff (768 f32)) + bias
//   Weff[ch, r*8+p, c*8+q] = sum_{P,Q} lhs[r,P,p] * rhs[c,q,Q]
//                            * W[ch*1024 + (r*16+P)*32 + (c*16+Q)]
//
// R7: persistent single-generation structure. 1024 blocks (exactly 4/CU
// resident at t=0), 32 rows/block, 8 rows/wave in 4 pipelined iterations
// of 2 rows. ONE contraction bubble per block (hipcc drains vmcnt(0) at
// every s_barrier - unavoidable), then a barrier-free register-double-
// buffered streaming loop: consume iter t, issue iter t+2, reduce/store.
// Removes R6's second generation (relaunch gap + second contraction).

#define BATCH 32768
#define ROW_F4 192              // 768 floats per sample in float4 units
#define ROWS_PER_BLOCK 32
#define GRID_BLOCKS (BATCH / ROWS_PER_BLOCK)   // 1024

__device__ __forceinline__ float dot4(const float4& a, const float4& b) {
    return a.x * b.x + a.y * b.y + a.z * b.z + a.w * b.w;
}

// Merged 2-row wave64 reduction: 6 shfl; lanes 0/1 store rows 0/1.
__device__ __forceinline__ void reduce2_store(float a0, float a1, int lane,
                                              float* __restrict__ outp,
                                              float bias) {
    a0 += __shfl_xor(a0, 1);
    a1 += __shfl_xor(a1, 1);
    float b = (lane & 1) ? a1 : a0;    // parity selects row
    b += __shfl_xor(b, 2);
    b += __shfl_xor(b, 4);
    b += __shfl_xor(b, 8);
    b += __shfl_xor(b, 16);
    b += __shfl_xor(b, 32);
    if (lane < 2) outp[lane] = b + bias;
}

__global__ __launch_bounds__(256, 4) void fused_compressor_kernel(
        const float4* __restrict__ x4,
        const float4* __restrict__ lhs4,   // 64 float4
        const float4* __restrict__ rhs4,   // 64 float4
        const float4* __restrict__ W4,     // 768 float4
        const float* __restrict__ bptr,
        float* __restrict__ out) {
    __shared__ __align__(16) float Wl[3072];    // W copy (12 KB)
    __shared__ __align__(16) float rh[256];     // rhs copy
    __shared__ __align__(16) float lh[256];     // lhs copy
    __shared__ float tmp[1536];                 // [ch][R(32)][j(16)]
    __shared__ __align__(16) float weff[768];   // [ch][i(16)][j(16)]

    const int tid  = threadIdx.x;
    const int lane = tid & 63;
    const int w    = tid >> 6;

    const int wrow = blockIdx.x * ROWS_PER_BLOCK + w * 8;   // 8 rows per wave

    // ---- prologue: issue iters 0,1 x loads (12 x 1KB per wave) ----
    const float4* xr = x4 + (size_t)wrow * ROW_F4 + lane;
    float4 xa[2][3], xb[2][3];
    #pragma unroll
    for (int r = 0; r < 2; ++r)
        #pragma unroll
        for (int k = 0; k < 3; ++k)
            xa[r][k] = xr[r * ROW_F4 + k * 64];            // rows 0,1
    #pragma unroll
    for (int r = 0; r < 2; ++r)
        #pragma unroll
        for (int k = 0; k < 3; ++k)
            xb[r][k] = xr[(2 + r) * ROW_F4 + k * 64];      // rows 2,3

    // ---- param loads (4 per thread, branch-free) ----
    float4 wreg0 = W4[tid];
    float4 wreg1 = W4[tid + 256];
    float4 wreg2 = W4[tid + 512];
    int sidx = tid & 127;
    float4 sreg = (sidx < 64) ? rhs4[sidx] : lhs4[sidx - 64];

    reinterpret_cast<float4*>(Wl)[tid]       = wreg0;
    reinterpret_cast<float4*>(Wl)[tid + 256] = wreg1;
    reinterpret_cast<float4*>(Wl)[tid + 512] = wreg2;
    if (tid < 128) {
        if (tid < 64) reinterpret_cast<float4*>(rh)[tid] = sreg;
        else          reinterpret_cast<float4*>(lh)[tid - 64] = sreg;
    }
    __syncthreads();   // drains vmcnt(0): prologue x arrives here (productive)

    // ---- stage A (LDS): tmp[ch,R,j] = sum_Q rhs[c,q,Q]*W[ch,R,c*16+Q] ----
    const float4* rhv = reinterpret_cast<const float4*>(rh);
    const float4* Wlv = reinterpret_cast<const float4*>(Wl);
    #pragma unroll
    for (int s = 0; s < 6; ++s) {
        int idx = tid + (s << 8);           // 0..1535
        int ch  = idx >> 9;
        int rem = idx & 511;
        int R   = rem >> 4;
        int j   = rem & 15;
        int c   = j >> 3;
        int q   = j & 7;
        const float4* rp = rhv + c * 32 + q * 4;             // 16 floats
        const float4* wp = Wlv + ch * 256 + R * 8 + c * 4;   // 16 floats
        tmp[idx] = dot4(rp[0], wp[0]) + dot4(rp[1], wp[1])
                 + dot4(rp[2], wp[2]) + dot4(rp[3], wp[3]);
    }
    __syncthreads();

    // ---- stage B (LDS): weff[ch,i,j] = sum_P lhs[r,P,p]*tmp[ch,r*16+P,j] ----
    #pragma unroll
    for (int s = 0; s < 3; ++s) {
        int idx = tid + (s << 8);           // 0..767
        int ch  = idx >> 8;
        int rem = idx & 255;
        int i   = rem >> 4;
        int j   = rem & 15;
        int r   = i >> 3;
        int p   = i & 7;
        const float* lp = lh + r * 128 + p;
        const float* tp = tmp + ch * 512 + r * 256 + j;
        float acc = 0.f;
        #pragma unroll
        for (int P = 0; P < 16; ++P) acc += lp[P * 8] * tp[P * 16];
        weff[idx] = acc;
    }
    __syncthreads();   // last barrier; loop below is barrier-free

    // ---- per-lane weight fragment (LDS) + bias ----
    const float4* wv4 = reinterpret_cast<const float4*>(weff);
    const float4 wv0 = wv4[lane];
    const float4 wv1 = wv4[lane + 64];
    const float4 wv2 = wv4[lane + 128];
    const float  bias = bptr[0];

    // ---- pipelined streaming loop: 4 iters x 2 rows, depth-2 prefetch ----
    // t=0: consume xa (rows 0,1); reload xa <- rows 4,5
    {
        float a0 = dot4(xa[0][0], wv0) + dot4(xa[0][1], wv1) + dot4(xa[0][2], wv2);
        float a1 = dot4(xa[1][0], wv0) + dot4(xa[1][1], wv1) + dot4(xa[1][2], wv2);
        #pragma unroll
        for (int r = 0; r < 2; ++r)
            #pragma unroll
            for (int k = 0; k < 3; ++k)
                xa[r][k] = xr[(4 + r) * ROW_F4 + k * 64];
        reduce2_store(a0, a1, lane, out + wrow, bias);
    }
    // t=1: consume xb (rows 2,3); reload xb <- rows 6,7
    {
        float a0 = dot4(xb[0][0], wv0) + dot4(xb[0][1], wv1) + dot4(xb[0][2], wv2);
        float a1 = dot4(xb[1][0], wv0) + dot4(xb[1][1], wv1) + dot4(xb[1][2], wv2);
        #pragma unroll
        for (int r = 0; r < 2; ++r)
            #pragma unroll
            for (int k = 0; k < 3; ++k)
                xb[r][k] = xr[(6 + r) * ROW_F4 + k * 64];
        reduce2_store(a0, a1, lane, out + wrow + 2, bias);
    }
    // t=2: consume xa (rows 4,5)
    {
        float a0 = dot4(xa[0][0], wv0) + dot4(xa[0][1], wv1) + dot4(xa[0][2], wv2);
        float a1 = dot4(xa[1][0], wv0) + dot4(xa[1][1], wv1) + dot4(xa[1][2], wv2);
        reduce2_store(a0, a1, lane, out + wrow + 4, bias);
    }
    // t=3: consume xb (rows 6,7)
    {
        float a0 = dot4(xb[0][0], wv0) + dot4(xb[0][1], wv1) + dot4(xb[0][2], wv2);
        float a1 = dot4(xb[1][0], wv0) + dot4(xb[1][1], wv1) + dot4(xb[1][2], wv2);
        reduce2_store(a0, a1, lane, out + wrow + 6, bias);
    }
}

extern "C" void kernel_launch(void* const* d_in, const int* in_sizes, int n_in,
                              void* d_out, int out_size, void* d_ws, size_t ws_size,
                              hipStream_t stream) {
    const float* x   = (const float*)d_in[0];   // [32768, 3, 16, 16]
    const float* lhs = (const float*)d_in[1];   // [2, 16, 8]
    const float* rhs = (const float*)d_in[2];   // [2, 8, 16]
    const float* W   = (const float*)d_in[3];   // [1, 3072]
    const float* b   = (const float*)d_in[4];   // [1]
    float* out = (float*)d_out;                 // [32768]

    fused_compressor_kernel<<<GRID_BLOCKS, 256, 0, stream>>>(
        (const float4*)x, (const float4*)lhs, (const float4*)rhs,
        (const float4*)W, b, out);
}